// Round 20
// baseline (733.160 us; speedup 1.0000x reference)
//
#include <hip/hip_runtime.h>
#include <hip/hip_bf16.h>

typedef __bf16 bf16x8 __attribute__((ext_vector_type(8)));
typedef float  f32x4  __attribute__((ext_vector_type(4)));
typedef unsigned short u16;

#define GLDS16(gsrc, ldst)                                                        \
  __builtin_amdgcn_global_load_lds(                                               \
      (const __attribute__((address_space(1))) unsigned int*)(gsrc),              \
      (__attribute__((address_space(3))) unsigned int*)(ldst), 16, 0, 0)

#define BAR() __builtin_amdgcn_s_barrier()
#define WAIT_LGKM0() asm volatile("s_waitcnt lgkmcnt(0)" ::: "memory")
#define WAIT_VM0() asm volatile("s_waitcnt vmcnt(0)" ::: "memory")
#define WAIT_VM4() asm volatile("s_waitcnt vmcnt(4)" ::: "memory")

__device__ __forceinline__ u16 f2b(float f) {
  unsigned int u = __builtin_bit_cast(unsigned int, f);
  u = (u + 0x7fffu + ((u >> 16) & 1u)) >> 16;
  return (u16)u;
}
__device__ __forceinline__ float b2f(u16 b) {
  unsigned int u = ((unsigned int)b) << 16;
  return __builtin_bit_cast(float, u);
}

__device__ __forceinline__ bf16x8 cvt8(const float* p) {
  float4 f0 = *(const float4*)p;
  float4 f1 = *(const float4*)(p + 4);
  bf16x8 v;
  v[0] = (__bf16)f0.x; v[1] = (__bf16)f0.y; v[2] = (__bf16)f0.z; v[3] = (__bf16)f0.w;
  v[4] = (__bf16)f1.x; v[5] = (__bf16)f1.y; v[6] = (__bf16)f1.z; v[7] = (__bf16)f1.w;
  return v;
}

// ---- fused: x/Wg/Wu fp32->bf16 convert + x-LoRA rank-projection (tail blocks) ----
// blocks 0-511: x cvt; 512-2559: Wg; 2560-4607: Wu;
// blocks 4608-4735: tg/tu = 0.5 * x @ A^T (reads x fp32 directly; 16 rows/block).
__global__ __launch_bounds__(256) void cvt3l_kernel(
    const float* __restrict__ xf,   ushort4* __restrict__ xb,
    const float4* __restrict__ wgf, ushort4* __restrict__ wgb,
    const float4* __restrict__ wuf, ushort4* __restrict__ wub,
    const float* __restrict__ Ag,   const float* __restrict__ Au,
    const int* __restrict__ lidx,   const int* __restrict__ layer,
    u16* __restrict__ tg, u16* __restrict__ tu) {
  __shared__ float red1[4][64][4];
  __shared__ float red2[4][64][4];
  if (blockIdx.x >= 4608) {  // ---- x-LoRA tail ----
    constexpr int K = 4096;
    const int lane = threadIdx.x & 63, wid = threadIdx.x >> 6;
    const int m0 = (blockIdx.x - 4608) * 16;
    const int li = lidx[m0 >> 9];
    const size_t abase = ((size_t)layer[0] * 16 + li) * 16 * (size_t)K;
    const int r = lane & 15, kg = lane >> 4;
    const int Kq = K >> 2, kb = wid * Kq;
    f32x4 acc1 = {0.f, 0.f, 0.f, 0.f}, acc2 = {0.f, 0.f, 0.f, 0.f};
    for (int k0 = kb; k0 < kb + Kq; k0 += 32) {
      bf16x8 a = cvt8(xf + (size_t)(m0 + r) * K + k0 + kg * 8);
      bf16x8 b1 = cvt8(Ag + abase + (size_t)r * K + k0 + kg * 8);
      bf16x8 b2 = cvt8(Au + abase + (size_t)r * K + k0 + kg * 8);
      acc1 = __builtin_amdgcn_mfma_f32_16x16x32_bf16(a, b1, acc1, 0, 0, 0);
      acc2 = __builtin_amdgcn_mfma_f32_16x16x32_bf16(a, b2, acc2, 0, 0, 0);
    }
#pragma unroll
    for (int j = 0; j < 4; ++j) {
      red1[wid][lane][j] = acc1[j];
      red2[wid][lane][j] = acc2[j];
    }
    __syncthreads();
    if (wid == 0) {
#pragma unroll
      for (int j = 0; j < 4; ++j) {
        int m = m0 + kg * 4 + j;
        float v1 = red1[0][lane][j] + red1[1][lane][j] + red1[2][lane][j] + red1[3][lane][j];
        float v2 = red2[0][lane][j] + red2[1][lane][j] + red2[2][lane][j] + red2[3][lane][j];
        tg[(size_t)m * 16 + r] = f2b(0.5f * v1);
        tu[(size_t)m * 16 + r] = f2b(0.5f * v2);
      }
    }
    return;
  }
  // ---- convert section ----
  const float4* in; ushort4* out; int i, stride, n4;
  if (blockIdx.x < 512) {
    in = (const float4*)xf; out = xb; n4 = 2097152;
    i = blockIdx.x * 256 + threadIdx.x; stride = 512 * 256;
  } else if (blockIdx.x < 2560) {
    in = wgf; out = wgb; n4 = 11272192;
    i = (blockIdx.x - 512) * 256 + threadIdx.x; stride = 2048 * 256;
  } else {
    in = wuf; out = wub; n4 = 11272192;
    i = (blockIdx.x - 2560) * 256 + threadIdx.x; stride = 2048 * 256;
  }
  for (; i < n4; i += stride) {
    float4 v = in[i];
    ushort4 o;
    o.x = f2b(v.x); o.y = f2b(v.y); o.z = f2b(v.z); o.w = f2b(v.w);
    out[i] = o;
  }
}

// ------ LoRA rank-projection (act pass, bf16 input): td = 0.5 * act @ Ad^T ------
__global__ __launch_bounds__(256) void lora_t2(const u16* __restrict__ Xb, int K,
                                               const float* __restrict__ A1,
                                               const int* __restrict__ lidx,
                                               const int* __restrict__ layer,
                                               u16* __restrict__ t1) {
  __shared__ float red1[4][64][4];
  const int lane = threadIdx.x & 63, wid = threadIdx.x >> 6;
  const int m0 = blockIdx.x * 16;
  const int li = lidx[m0 >> 9];
  const size_t abase = ((size_t)layer[0] * 16 + li) * 16 * (size_t)K;
  const int r = lane & 15, kg = lane >> 4;
  const int Kq = K >> 2, kb = wid * Kq;
  f32x4 acc1 = {0.f, 0.f, 0.f, 0.f};
  for (int k0 = kb; k0 < kb + Kq; k0 += 32) {
    bf16x8 a = *(const bf16x8*)&Xb[(size_t)(m0 + r) * K + k0 + kg * 8];
    bf16x8 b = cvt8(A1 + abase + (size_t)r * K + k0 + kg * 8);
    acc1 = __builtin_amdgcn_mfma_f32_16x16x32_bf16(a, b, acc1, 0, 0, 0);
  }
#pragma unroll
  for (int j = 0; j < 4; ++j) red1[wid][lane][j] = acc1[j];
  __syncthreads();
  if (wid == 0) {
#pragma unroll
    for (int j = 0; j < 4; ++j) {
      int m = m0 + kg * 4 + j;
      float v1 = red1[0][lane][j] + red1[1][lane][j] + red1[2][lane][j] + red1[3][lane][j];
      t1[(size_t)m * 16 + r] = f2b(0.5f * v1);
    }
  }
}

// ===================== shared tile macros =====================
#define RD_A(dst, buf, mh) do {                                                \
    _Pragma("unroll")                                                          \
    for (int mf_ = 0; mf_ < 4; ++mf_)                                          \
      _Pragma("unroll")                                                        \
      for (int ks_ = 0; ks_ < 2; ++ks_) {                                      \
        int row_ = wm * 128 + (mh) * 64 + mf_ * 16 + lr;                       \
        int sl_ = (ks_ * 4 + kg) ^ rx;                                         \
        dst[mf_][ks_] = *(const bf16x8*)&sA[(buf) * 16384 + row_ * 64 + sl_ * 8]; \
      }                                                                        \
  } while (0)

#define RD_BW(dst, SB, buf) do {                                               \
    _Pragma("unroll")                                                          \
    for (int nf_ = 0; nf_ < 2; ++nf_)                                          \
      _Pragma("unroll")                                                        \
      for (int ks_ = 0; ks_ < 2; ++ks_) {                                      \
        int row_ = wn * 32 + nf_ * 16 + lr;                                    \
        int sl_ = (ks_ * 4 + kg) ^ rx;                                         \
        dst[nf_][ks_] = *(const bf16x8*)&SB[(buf) * 8192 + row_ * 64 + sl_ * 8]; \
      }                                                                        \
  } while (0)

#define MMA_F(AF, BF, ACC, mb) do {                                            \
    __builtin_amdgcn_s_setprio(1);                                             \
    _Pragma("unroll")                                                          \
    for (int mf_ = 0; mf_ < 4; ++mf_)                                          \
      _Pragma("unroll")                                                        \
      for (int nf_ = 0; nf_ < 2; ++nf_)                                        \
        _Pragma("unroll")                                                      \
        for (int ks_ = 0; ks_ < 2; ++ks_)                                      \
          ACC[(mb) + mf_][nf_] = __builtin_amdgcn_mfma_f32_16x16x32_bf16(      \
              AF[mf_][ks_], BF[nf_][ks_], ACC[(mb) + mf_][nf_], 0, 0, 0);      \
    __builtin_amdgcn_s_setprio(0);                                             \
  } while (0)

// ====== fused gate+up GEMM, tile 256m x 128n, output-stationary SwiGLU =========
#define STAGE_F(buf, half, kt) do {                                            \
    const u16* gs_; u16* ld_;                                                  \
    if ((half) == 0)      { gs_ = Xb + (size_t)m0 * 4096 + (size_t)(kt) * 64;         ld_ = sA  + (buf) * 16384; }        \
    else if ((half) == 1) { gs_ = Xb + (size_t)(m0 + 128) * 4096 + (size_t)(kt) * 64; ld_ = sA  + (buf) * 16384 + 8192; } \
    else if ((half) == 2) { gs_ = Wg + (size_t)n0 * 4096 + (size_t)(kt) * 64;         ld_ = sBG + (buf) * 8192; }         \
    else                  { gs_ = Wu + (size_t)n0 * 4096 + (size_t)(kt) * 64;         ld_ = sBU + (buf) * 8192; }         \
    _Pragma("unroll")                                                          \
    for (int i_ = 0; i_ < 2; ++i_) {                                           \
      int ub_ = (wid << 6) + i_ * 512;                                         \
      int un_ = ub_ + lane;                                                    \
      int ur_ = un_ >> 3, us_ = (un_ & 7) ^ (ur_ & 7);                         \
      GLDS16(gs_ + (size_t)ur_ * 4096 + us_ * 8, ld_ + ub_ * 8);               \
    }                                                                          \
  } while (0)

__global__ __launch_bounds__(512, 2) void gemm_gup_fused(
    const u16* __restrict__ Xb, const u16* __restrict__ Wg, const u16* __restrict__ Wu,
    const u16* __restrict__ tg, const u16* __restrict__ tu,
    const float* __restrict__ Bg, const float* __restrict__ Bu,
    const int* __restrict__ lidx, const int* __restrict__ layer,
    u16* __restrict__ act,
    const float4* __restrict__ Wdf, ushort4* __restrict__ wdb3) {
  constexpr int F = 11008;
  const int b = blockIdx.x;
  if (b >= 704) {  // Wd convert tail
    int i = (b - 704) * 512 + threadIdx.x;
    for (; i < 11272192; i += 256 * 512) {
      float4 v = Wdf[i];
      ushort4 o;
      o.x = f2b(v.x); o.y = f2b(v.y); o.z = f2b(v.z); o.w = f2b(v.w);
      wdb3[i] = o;
    }
    return;
  }
  const int xcd = b & 7, j = b >> 3;
  const int ny = xcd + 8 * (j >> 3);
  const int mx = j & 7;
  if (ny >= 86) return;
  extern __shared__ u16 smem[];
  u16* sA  = smem;                    // [2][256*64]  64 KB
  u16* sBG = smem + 32768;            // [2][128*64]  32 KB
  u16* sBU = smem + 49152;            // [2][128*64]  32 KB
  const int tid = threadIdx.x, lane = tid & 63, wid = tid >> 6;
  const int lr = lane & 15, kg = lane >> 4, rx = lr & 7;
  const int wm = wid >> 2, wn = wid & 3;
  const int m0 = mx * 256;
  const int n0 = ny * 128;

  f32x4 accg[8][2] = {}, accu[8][2] = {};
  bf16x8 a0[4][2], a1[4][2], bg[2][2], bu[2][2];

  STAGE_F(0, 0, 0); STAGE_F(0, 1, 0); STAGE_F(0, 2, 0); STAGE_F(0, 3, 0);
  STAGE_F(1, 2, 1); STAGE_F(1, 3, 1);
  WAIT_VM4(); BAR();

#pragma unroll 1
  for (int u = 0; u < 32; ++u) {
    const int ktA = (2 * u + 1) & 63;
    const int kt0 = (2 * u + 2) & 63;
    const int kt1 = (2 * u + 3) & 63;
    RD_A(a0, 0, 0); RD_BW(bg, sBG, 0);
    STAGE_F(1, 0, ktA);
    BAR(); WAIT_LGKM0();
    MMA_F(a0, bg, accg, 0);
    BAR();
    RD_BW(bu, sBU, 0);
    STAGE_F(1, 1, ktA);
    BAR(); WAIT_LGKM0();
    MMA_F(a0, bu, accu, 0);
    BAR();
    RD_A(a1, 0, 1);
    STAGE_F(0, 2, kt0);
    BAR(); WAIT_LGKM0();
    MMA_F(a1, bu, accu, 4);
    BAR();
    STAGE_F(0, 3, kt0);
    BAR();
    MMA_F(a1, bg, accg, 4);
    WAIT_VM4();
    BAR();
    RD_A(a0, 1, 0); RD_BW(bg, sBG, 1);
    STAGE_F(0, 0, kt0); STAGE_F(0, 1, kt0);
    BAR(); WAIT_LGKM0();
    MMA_F(a0, bg, accg, 0);
    BAR();
    RD_BW(bu, sBU, 1);
    BAR(); WAIT_LGKM0();
    MMA_F(a0, bu, accu, 0);
    BAR();
    RD_A(a1, 1, 1);
    STAGE_F(1, 2, kt1);
    BAR(); WAIT_LGKM0();
    MMA_F(a1, bu, accu, 4);
    BAR();
    STAGE_F(1, 3, kt1);
    BAR();
    MMA_F(a1, bg, accg, 4);
    WAIT_VM4();
    BAR();
  }

  // ---- LoRA via MFMA (gate, then up), then silu(g)*u store ----
  const int li = lidx[m0 >> 9];
  const size_t bbase = ((size_t)layer[0] * 16 + li) * (size_t)F * 16;
  bf16x8 la[8], lb[2];
  const bf16x8 zz = {};
#pragma unroll
  for (int mf = 0; mf < 8; ++mf) {
    int row = m0 + wm * 128 + mf * 16 + lr;
    la[mf] = (kg < 2) ? *(const bf16x8*)&tg[(size_t)row * 16 + kg * 8] : zz;
  }
#pragma unroll
  for (int nf = 0; nf < 2; ++nf) {
    int col = n0 + wn * 32 + nf * 16 + lr;
    lb[nf] = (kg < 2) ? cvt8(Bg + bbase + (size_t)col * 16 + kg * 8) : zz;
  }
#pragma unroll
  for (int mf = 0; mf < 8; ++mf)
#pragma unroll
    for (int nf = 0; nf < 2; ++nf)
      accg[mf][nf] = __builtin_amdgcn_mfma_f32_16x16x32_bf16(la[mf], lb[nf], accg[mf][nf], 0, 0, 0);
#pragma unroll
  for (int mf = 0; mf < 8; ++mf) {
    int row = m0 + wm * 128 + mf * 16 + lr;
    la[mf] = (kg < 2) ? *(const bf16x8*)&tu[(size_t)row * 16 + kg * 8] : zz;
  }
#pragma unroll
  for (int nf = 0; nf < 2; ++nf) {
    int col = n0 + wn * 32 + nf * 16 + lr;
    lb[nf] = (kg < 2) ? cvt8(Bu + bbase + (size_t)col * 16 + kg * 8) : zz;
  }
#pragma unroll
  for (int mf = 0; mf < 8; ++mf)
#pragma unroll
    for (int nf = 0; nf < 2; ++nf)
      accu[mf][nf] = __builtin_amdgcn_mfma_f32_16x16x32_bf16(la[mf], lb[nf], accu[mf][nf], 0, 0, 0);

#pragma unroll
  for (int mf = 0; mf < 8; ++mf)
#pragma unroll
    for (int nf = 0; nf < 2; ++nf)
#pragma unroll
      for (int j2 = 0; j2 < 4; ++j2) {
        int row = m0 + wm * 128 + mf * 16 + kg * 4 + j2;
        int col = n0 + wn * 32 + nf * 16 + lr;
        float g = accg[mf][nf][j2], uu = accu[mf][nf][j2];
        float s = g / (1.f + __expf(-g));
        act[(size_t)row * F + col] = f2b(s * uu);
      }
}

// ====== down GEMM, 256m x 128n, NO K-split, 4-phase/2-K-tile, fp32 out =========
#define STAGE_NA(buf, half, kt) do {                                           \
    const u16* gs_ = Ab + (size_t)(m0 + (half) * 128) * 11008 + (size_t)(kt) * 64; \
    u16* ld_ = sA + (buf) * 16384 + (half) * 8192;                             \
    _Pragma("unroll")                                                          \
    for (int i_ = 0; i_ < 2; ++i_) {                                           \
      int ub_ = (wid << 6) + i_ * 512;                                         \
      int un_ = ub_ + lane;                                                    \
      int ur_ = un_ >> 3, us_ = (un_ & 7) ^ (ur_ & 7);                         \
      GLDS16(gs_ + (size_t)ur_ * 11008 + us_ * 8, ld_ + ub_ * 8);              \
    }                                                                          \
  } while (0)

#define STAGE_NB(buf, kt) do {                                                 \
    const u16* gs_ = Wd + (size_t)n0 * 11008 + (size_t)(kt) * 64;              \
    u16* ld_ = sB + (buf) * 8192;                                              \
    _Pragma("unroll")                                                          \
    for (int i_ = 0; i_ < 2; ++i_) {                                           \
      int ub_ = (wid << 6) + i_ * 512;                                         \
      int un_ = ub_ + lane;                                                    \
      int ur_ = un_ >> 3, us_ = (un_ & 7) ^ (ur_ & 7);                         \
      GLDS16(gs_ + (size_t)ur_ * 11008 + us_ * 8, ld_ + ub_ * 8);              \
    }                                                                          \
  } while (0)

#define KTW(t) ((t) >= 172 ? (t) - 172 : (t))

__global__ __launch_bounds__(512, 2) void gemm_down_ns(
    const u16* __restrict__ Ab, const u16* __restrict__ Wd,
    const u16* __restrict__ td, const float* __restrict__ Bd,
    const int* __restrict__ lidx, const int* __restrict__ layer,
    float* __restrict__ out) {
  constexpr int H = 4096;
  extern __shared__ u16 smem[];
  u16* sA = smem;            // [2][256*64] 64 KB
  u16* sB = smem + 32768;    // [2][128*64] 32 KB
  const int b = blockIdx.x;
  const int xcd = b & 7, j = b >> 3;
  const int ny = xcd + 8 * (j >> 3);
  const int mx = j & 7;
  const int tid = threadIdx.x, lane = tid & 63, wid = tid >> 6;
  const int lr = lane & 15, kg = lane >> 4, rx = lr & 7;
  const int wm = wid >> 2, wn = wid & 3;
  const int m0 = mx * 256;
  const int n0 = ny * 128;

  f32x4 acc[8][2] = {};
  bf16x8 a0[4][2], a1[4][2], bw[2][2];

  STAGE_NA(0, 0, 0); STAGE_NA(0, 1, 0); STAGE_NB(0, 0);
  STAGE_NA(1, 0, 1); STAGE_NB(1, 1);
  WAIT_VM0(); BAR();

#pragma unroll 1
  for (int u = 0; u < 86; ++u) {
    const int ktA = KTW(2 * u + 1);
    const int kt0 = KTW(2 * u + 2);
    const int kt1 = KTW(2 * u + 3);
    RD_A(a0, 0, 0); RD_BW(bw, sB, 0);
    STAGE_NA(1, 1, ktA);
    BAR(); WAIT_LGKM0();
    MMA_F(a0, bw, acc, 0);
    BAR();
    RD_A(a1, 0, 1);
    STAGE_NA(0, 0, kt0); STAGE_NB(0, kt0);
    BAR(); WAIT_LGKM0();
    MMA_F(a1, bw, acc, 4);
    WAIT_VM4();
    BAR();
    RD_A(a0, 1, 0); RD_BW(bw, sB, 1);
    STAGE_NA(0, 1, kt0);
    BAR(); WAIT_LGKM0();
    MMA_F(a0, bw, acc, 0);
    BAR();
    RD_A(a1, 1, 1);
    STAGE_NA(1, 0, kt1); STAGE_NB(1, kt1);
    BAR(); WAIT_LGKM0();
    MMA_F(a1, bw, acc, 4);
    WAIT_VM4();
    BAR();
  }

  // ---- down-LoRA via MFMA, then fp32 store ----
  const int li = lidx[m0 >> 9];
  const size_t bbase = ((size_t)layer[0] * 16 + li) * (size_t)H * 16;
  bf16x8 la[8], lb[2];
  const bf16x8 zz = {};
#pragma unroll
  for (int mf = 0; mf < 8; ++mf) {
    int row = m0 + wm * 128 + mf * 16 + lr;
    la[mf] = (kg < 2) ? *(const bf16x8*)&td[(size_t)row * 16 + kg * 8] : zz;
  }
#pragma unroll
  for (int nf = 0; nf < 2; ++nf) {
    int col = n0 + wn * 32 + nf * 16 + lr;
    lb[nf] = (kg < 2) ? cvt8(Bd + bbase + (size_t)col * 16 + kg * 8) : zz;
  }
#pragma unroll
  for (int mf = 0; mf < 8; ++mf)
#pragma unroll
    for (int nf = 0; nf < 2; ++nf)
      acc[mf][nf] = __builtin_amdgcn_mfma_f32_16x16x32_bf16(la[mf], lb[nf], acc[mf][nf], 0, 0, 0);

#pragma unroll
  for (int mf = 0; mf < 8; ++mf)
#pragma unroll
    for (int nf = 0; nf < 2; ++nf)
#pragma unroll
      for (int j2 = 0; j2 < 4; ++j2) {
        int row = m0 + wm * 128 + mf * 16 + kg * 4 + j2;
        int col = n0 + wn * 32 + nf * 16 + lr;
        out[(size_t)row * H + col] = acc[mf][nf][j2];
      }
}

extern "C" void kernel_launch(void* const* d_in, const int* in_sizes, int n_in,
                              void* d_out, int out_size, void* d_ws, size_t ws_size,
                              hipStream_t stream) {
  const float* x  = (const float*)d_in[0];
  const float* Wg = (const float*)d_in[1];
  const float* Wu = (const float*)d_in[2];
  const float* Wd = (const float*)d_in[3];
  const float* Ag = (const float*)d_in[4];
  const float* Bg = (const float*)d_in[5];
  const float* Au = (const float*)d_in[6];
  const float* Bu = (const float*)d_in[7];
  const float* Ad = (const float*)d_in[8];
  const float* Bd = (const float*)d_in[9];
  const int* lidx = (const int*)d_in[10];
  const int* lay  = (const int*)d_in[11];
  float* out = (float*)d_out;

  char* ws = (char*)d_ws;
  u16*  xb   = (u16*)(ws + 0);            //  16,777,216  x bf16 [2048][4096]
  u16*  wgb  = (u16*)(ws + 16777216);     //  90,177,536  Wg bf16 [11008][4096]
  u16*  wub  = (u16*)(ws + 106954752);    //  90,177,536  Wu bf16
  u16*  gbuf = (u16*)(ws + 197132288);    //  45,088,768  act bf16 [2048][11008]
  u16*  tg   = (u16*)(ws + 287309824);    //  65,536
  u16*  tu   = (u16*)(ws + 287375360);    //  65,536
  u16*  td   = (u16*)(ws + 287440896);    //  65,536
  u16*  wdb3 = (u16*)(ws + 287506432);    //  90,177,536  Wd bf16

  hipFuncSetAttribute(reinterpret_cast<const void*>(gemm_gup_fused),
                      hipFuncAttributeMaxDynamicSharedMemorySize, 131072);
  hipFuncSetAttribute(reinterpret_cast<const void*>(gemm_down_ns),
                      hipFuncAttributeMaxDynamicSharedMemorySize, 98304);

  // converts + x-LoRA in one launch (lora tail blocks read x fp32 directly)
  cvt3l_kernel<<<4736, 256, 0, stream>>>(x, (ushort4*)xb,
                                         (const float4*)Wg, (ushort4*)wgb,
                                         (const float4*)Wu, (ushort4*)wub,
                                         Ag, Au, lidx, lay, tg, tu);

  gemm_gup_fused<<<dim3(960), 512, 131072, stream>>>(
      xb, wgb, wub, tg, tu, Bg, Bu, lidx, lay, gbuf,
      (const float4*)Wd, (ushort4*)wdb3);

  lora_t2<<<128, 256, 0, stream>>>(gbuf, 11008, Ad, lidx, lay, td);

  gemm_down_ns<<<dim3(256), 512, 98304, stream>>>(gbuf, wdb3, td, Bd, lidx, lay, out);
}

// Round 21
// 723.172 us; speedup vs baseline: 1.0138x; 1.0138x over previous
//
#include <hip/hip_runtime.h>
#include <hip/hip_bf16.h>

typedef __bf16 bf16x8 __attribute__((ext_vector_type(8)));
typedef float  f32x4  __attribute__((ext_vector_type(4)));
typedef unsigned short u16;

#define GLDS16(gsrc, ldst)                                                        \
  __builtin_amdgcn_global_load_lds(                                               \
      (const __attribute__((address_space(1))) unsigned int*)(gsrc),              \
      (__attribute__((address_space(3))) unsigned int*)(ldst), 16, 0, 0)

#define BAR() __builtin_amdgcn_s_barrier()
#define WAIT_LGKM0() asm volatile("s_waitcnt lgkmcnt(0)" ::: "memory")
#define WAIT_VM0() asm volatile("s_waitcnt vmcnt(0)" ::: "memory")
#define WAIT_VM4() asm volatile("s_waitcnt vmcnt(4)" ::: "memory")

__device__ __forceinline__ u16 f2b(float f) {
  unsigned int u = __builtin_bit_cast(unsigned int, f);
  u = (u + 0x7fffu + ((u >> 16) & 1u)) >> 16;
  return (u16)u;
}
__device__ __forceinline__ float b2f(u16 b) {
  unsigned int u = ((unsigned int)b) << 16;
  return __builtin_bit_cast(float, u);
}

// ------- fused fp32->bf16 convert: x (512 blks) + Wg (2048) + Wu (2048) --------
__global__ __launch_bounds__(256) void cvt3_kernel(
    const float4* __restrict__ xf,  ushort4* __restrict__ xb,
    const float4* __restrict__ wgf, ushort4* __restrict__ wgb,
    const float4* __restrict__ wuf, ushort4* __restrict__ wub) {
  const float4* in; ushort4* out; int i, stride, n4;
  if (blockIdx.x < 512) {
    in = xf; out = xb; n4 = 2097152;
    i = blockIdx.x * 256 + threadIdx.x; stride = 512 * 256;
  } else if (blockIdx.x < 2560) {
    in = wgf; out = wgb; n4 = 11272192;
    i = (blockIdx.x - 512) * 256 + threadIdx.x; stride = 2048 * 256;
  } else {
    in = wuf; out = wub; n4 = 11272192;
    i = (blockIdx.x - 2560) * 256 + threadIdx.x; stride = 2048 * 256;
  }
  for (; i < n4; i += stride) {
    float4 v = in[i];
    ushort4 o;
    o.x = f2b(v.x); o.y = f2b(v.y); o.z = f2b(v.z); o.w = f2b(v.w);
    out[i] = o;
  }
}

// ------ LoRA rank-projection, wave-K-split: t_bf16[m][r] = 0.5*sum_k Xb[m][k]*A[r][k]
__global__ __launch_bounds__(256) void lora_t2(const u16* __restrict__ Xb, int K,
                                               const float* __restrict__ A1,
                                               const float* __restrict__ A2,
                                               const int* __restrict__ lidx,
                                               const int* __restrict__ layer,
                                               u16* __restrict__ t1,
                                               u16* __restrict__ t2) {
  __shared__ float red1[4][64][4];
  __shared__ float red2[4][64][4];
  const int lane = threadIdx.x & 63, wid = threadIdx.x >> 6;
  const int m0 = blockIdx.x * 16;
  const int li = lidx[m0 >> 9];
  const size_t abase = ((size_t)layer[0] * 16 + li) * 16 * (size_t)K;
  const int r = lane & 15, kg = lane >> 4;
  const int Kq = K >> 2, kb = wid * Kq;
  f32x4 acc1 = {0.f, 0.f, 0.f, 0.f}, acc2 = {0.f, 0.f, 0.f, 0.f};
  for (int k0 = kb; k0 < kb + Kq; k0 += 32) {
    bf16x8 a = *(const bf16x8*)&Xb[(size_t)(m0 + r) * K + k0 + kg * 8];
    const float* ap = A1 + abase + (size_t)r * K + k0 + kg * 8;
    float4 f0 = *(const float4*)ap;
    float4 f1 = *(const float4*)(ap + 4);
    bf16x8 b;
    b[0] = (__bf16)f0.x; b[1] = (__bf16)f0.y; b[2] = (__bf16)f0.z; b[3] = (__bf16)f0.w;
    b[4] = (__bf16)f1.x; b[5] = (__bf16)f1.y; b[6] = (__bf16)f1.z; b[7] = (__bf16)f1.w;
    acc1 = __builtin_amdgcn_mfma_f32_16x16x32_bf16(a, b, acc1, 0, 0, 0);
    if (A2) {
      const float* ap2 = A2 + abase + (size_t)r * K + k0 + kg * 8;
      float4 g0 = *(const float4*)ap2;
      float4 g1 = *(const float4*)(ap2 + 4);
      bf16x8 b2;
      b2[0] = (__bf16)g0.x; b2[1] = (__bf16)g0.y; b2[2] = (__bf16)g0.z; b2[3] = (__bf16)g0.w;
      b2[4] = (__bf16)g1.x; b2[5] = (__bf16)g1.y; b2[6] = (__bf16)g1.z; b2[7] = (__bf16)g1.w;
      acc2 = __builtin_amdgcn_mfma_f32_16x16x32_bf16(a, b2, acc2, 0, 0, 0);
    }
  }
#pragma unroll
  for (int j = 0; j < 4; ++j) {
    red1[wid][lane][j] = acc1[j];
    if (A2) red2[wid][lane][j] = acc2[j];
  }
  __syncthreads();
  if (wid == 0) {
#pragma unroll
    for (int j = 0; j < 4; ++j) {
      int m = m0 + kg * 4 + j;
      float v1 = red1[0][lane][j] + red1[1][lane][j] + red1[2][lane][j] + red1[3][lane][j];
      t1[(size_t)m * 16 + r] = f2b(0.5f * v1);
      if (A2) {
        float v2 = red2[0][lane][j] + red2[1][lane][j] + red2[2][lane][j] + red2[3][lane][j];
        t2[(size_t)m * 16 + r] = f2b(0.5f * v2);
      }
    }
  }
}

// ===================== shared 8-phase tile macros =====================
#define RD_A(dst, buf, mh) do {                                                \
    _Pragma("unroll")                                                          \
    for (int mf_ = 0; mf_ < 4; ++mf_)                                          \
      _Pragma("unroll")                                                        \
      for (int ks_ = 0; ks_ < 2; ++ks_) {                                      \
        int row_ = wm * 128 + (mh) * 64 + mf_ * 16 + lr;                       \
        int sl_ = (ks_ * 4 + kg) ^ rx;                                         \
        dst[mf_][ks_] = *(const bf16x8*)&sA[(buf) * 16384 + row_ * 64 + sl_ * 8]; \
      }                                                                        \
  } while (0)

// B-read: 128-row weight tile, per-wave 32 rows.
#define RD_BW(dst, SB, buf) do {                                               \
    _Pragma("unroll")                                                          \
    for (int nf_ = 0; nf_ < 2; ++nf_)                                          \
      _Pragma("unroll")                                                        \
      for (int ks_ = 0; ks_ < 2; ++ks_) {                                      \
        int row_ = wn * 32 + nf_ * 16 + lr;                                    \
        int sl_ = (ks_ * 4 + kg) ^ rx;                                         \
        dst[nf_][ks_] = *(const bf16x8*)&SB[(buf) * 8192 + row_ * 64 + sl_ * 8]; \
      }                                                                        \
  } while (0)

#define MMA_F(AF, BF, ACC, mb) do {                                            \
    __builtin_amdgcn_s_setprio(1);                                             \
    _Pragma("unroll")                                                          \
    for (int mf_ = 0; mf_ < 4; ++mf_)                                          \
      _Pragma("unroll")                                                        \
      for (int nf_ = 0; nf_ < 2; ++nf_)                                        \
        _Pragma("unroll")                                                      \
        for (int ks_ = 0; ks_ < 2; ++ks_)                                      \
          ACC[(mb) + mf_][nf_] = __builtin_amdgcn_mfma_f32_16x16x32_bf16(      \
              AF[mf_][ks_], BF[nf_][ks_], ACC[(mb) + mf_][nf_], 0, 0, 0);      \
    __builtin_amdgcn_s_setprio(0);                                             \
  } while (0)

// ====== fused gate+up GEMM, tile 256m x 128n, output-stationary SwiGLU =========
#define STAGE_F(buf, half, kt) do {                                            \
    const u16* gs_; u16* ld_;                                                  \
    if ((half) == 0)      { gs_ = Xb + (size_t)m0 * 4096 + (size_t)(kt) * 64;         ld_ = sA  + (buf) * 16384; }        \
    else if ((half) == 1) { gs_ = Xb + (size_t)(m0 + 128) * 4096 + (size_t)(kt) * 64; ld_ = sA  + (buf) * 16384 + 8192; } \
    else if ((half) == 2) { gs_ = Wg + (size_t)n0 * 4096 + (size_t)(kt) * 64;         ld_ = sBG + (buf) * 8192; }         \
    else                  { gs_ = Wu + (size_t)n0 * 4096 + (size_t)(kt) * 64;         ld_ = sBU + (buf) * 8192; }         \
    _Pragma("unroll")                                                          \
    for (int i_ = 0; i_ < 2; ++i_) {                                           \
      int ub_ = (wid << 6) + i_ * 512;                                         \
      int un_ = ub_ + lane;                                                    \
      int ur_ = un_ >> 3, us_ = (un_ & 7) ^ (ur_ & 7);                         \
      GLDS16(gs_ + (size_t)ur_ * 4096 + us_ * 8, ld_ + ub_ * 8);               \
    }                                                                          \
  } while (0)

// Blocks 0..703: fused GEMM (8 m-tiles x 88 padded n-tiles of 128, XCD-grouped).
// Blocks 704..959: convert Wd fp32->bf16 into wdb3 (fills the GEMM tail wave).
__global__ __launch_bounds__(512, 2) void gemm_gup_fused(
    const u16* __restrict__ Xb, const u16* __restrict__ Wg, const u16* __restrict__ Wu,
    const u16* __restrict__ tg, const u16* __restrict__ tu,
    const float* __restrict__ Bg, const float* __restrict__ Bu,
    const int* __restrict__ lidx, const int* __restrict__ layer,
    u16* __restrict__ act,
    const float4* __restrict__ Wdf, ushort4* __restrict__ wdb3) {
  constexpr int F = 11008;
  const int b = blockIdx.x;
  if (b >= 704) {  // Wd convert tail
    int i = (b - 704) * 512 + threadIdx.x;
    for (; i < 11272192; i += 256 * 512) {
      float4 v = Wdf[i];
      ushort4 o;
      o.x = f2b(v.x); o.y = f2b(v.y); o.z = f2b(v.z); o.w = f2b(v.w);
      wdb3[i] = o;
    }
    return;
  }
  const int xcd = b & 7, j = b >> 3;
  const int ny = xcd + 8 * (j >> 3);
  const int mx = j & 7;
  if (ny >= 86) return;
  extern __shared__ u16 smem[];
  u16* sA  = smem;                    // [2][256*64]  64 KB
  u16* sBG = smem + 32768;            // [2][128*64]  32 KB
  u16* sBU = smem + 49152;            // [2][128*64]  32 KB
  const int tid = threadIdx.x, lane = tid & 63, wid = tid >> 6;
  const int lr = lane & 15, kg = lane >> 4, rx = lr & 7;
  const int wm = wid >> 2, wn = wid & 3;
  const int m0 = mx * 256;
  const int n0 = ny * 128;

  f32x4 accg[8][2] = {}, accu[8][2] = {};
  bf16x8 a0[4][2], a1[4][2], bg[2][2], bu[2][2];

  STAGE_F(0, 0, 0); STAGE_F(0, 1, 0); STAGE_F(0, 2, 0); STAGE_F(0, 3, 0);
  STAGE_F(1, 2, 1); STAGE_F(1, 3, 1);
  WAIT_VM4(); BAR();

#pragma unroll 1
  for (int u = 0; u < 32; ++u) {
    const int ktA = (2 * u + 1) & 63;
    const int kt0 = (2 * u + 2) & 63;
    const int kt1 = (2 * u + 3) & 63;
    // g1
    RD_A(a0, 0, 0); RD_BW(bg, sBG, 0);
    STAGE_F(1, 0, ktA);
    BAR(); WAIT_LGKM0();
    MMA_F(a0, bg, accg, 0);
    BAR();
    // g2
    RD_BW(bu, sBU, 0);
    STAGE_F(1, 1, ktA);
    BAR(); WAIT_LGKM0();
    MMA_F(a0, bu, accu, 0);
    BAR();
    // g3
    RD_A(a1, 0, 1);
    STAGE_F(0, 2, kt0);
    BAR(); WAIT_LGKM0();
    MMA_F(a1, bu, accu, 4);
    BAR();
    // g4
    STAGE_F(0, 3, kt0);
    BAR();
    MMA_F(a1, bg, accg, 4);
    WAIT_VM4();
    BAR();
    // g5
    RD_A(a0, 1, 0); RD_BW(bg, sBG, 1);
    STAGE_F(0, 0, kt0); STAGE_F(0, 1, kt0);
    BAR(); WAIT_LGKM0();
    MMA_F(a0, bg, accg, 0);
    BAR();
    // g6
    RD_BW(bu, sBU, 1);
    BAR(); WAIT_LGKM0();
    MMA_F(a0, bu, accu, 0);
    BAR();
    // g7
    RD_A(a1, 1, 1);
    STAGE_F(1, 2, kt1);
    BAR(); WAIT_LGKM0();
    MMA_F(a1, bu, accu, 4);
    BAR();
    // g8
    STAGE_F(1, 3, kt1);
    BAR();
    MMA_F(a1, bg, accg, 4);
    WAIT_VM4();
    BAR();
  }

  // ---- LoRA via MFMA (gate, then up), then silu(g)*u store ----
  const int li = lidx[m0 >> 9];
  const size_t bbase = ((size_t)layer[0] * 16 + li) * (size_t)F * 16;
  bf16x8 la[8], lb[2];
  const bf16x8 zz = {};
#pragma unroll
  for (int mf = 0; mf < 8; ++mf) {
    int row = m0 + wm * 128 + mf * 16 + lr;
    la[mf] = (kg < 2) ? *(const bf16x8*)&tg[(size_t)row * 16 + kg * 8] : zz;
  }
#pragma unroll
  for (int nf = 0; nf < 2; ++nf) {
    int col = n0 + wn * 32 + nf * 16 + lr;
    if (kg < 2) {
      const float* bp = Bg + bbase + (size_t)col * 16 + kg * 8;
      float4 f0 = *(const float4*)bp;
      float4 f1 = *(const float4*)(bp + 4);
      bf16x8 v;
      v[0] = (__bf16)f0.x; v[1] = (__bf16)f0.y; v[2] = (__bf16)f0.z; v[3] = (__bf16)f0.w;
      v[4] = (__bf16)f1.x; v[5] = (__bf16)f1.y; v[6] = (__bf16)f1.z; v[7] = (__bf16)f1.w;
      lb[nf] = v;
    } else lb[nf] = zz;
  }
#pragma unroll
  for (int mf = 0; mf < 8; ++mf)
#pragma unroll
    for (int nf = 0; nf < 2; ++nf)
      accg[mf][nf] = __builtin_amdgcn_mfma_f32_16x16x32_bf16(la[mf], lb[nf], accg[mf][nf], 0, 0, 0);
#pragma unroll
  for (int mf = 0; mf < 8; ++mf) {
    int row = m0 + wm * 128 + mf * 16 + lr;
    la[mf] = (kg < 2) ? *(const bf16x8*)&tu[(size_t)row * 16 + kg * 8] : zz;
  }
#pragma unroll
  for (int nf = 0; nf < 2; ++nf) {
    int col = n0 + wn * 32 + nf * 16 + lr;
    if (kg < 2) {
      const float* bp = Bu + bbase + (size_t)col * 16 + kg * 8;
      float4 f0 = *(const float4*)bp;
      float4 f1 = *(const float4*)(bp + 4);
      bf16x8 v;
      v[0] = (__bf16)f0.x; v[1] = (__bf16)f0.y; v[2] = (__bf16)f0.z; v[3] = (__bf16)f0.w;
      v[4] = (__bf16)f1.x; v[5] = (__bf16)f1.y; v[6] = (__bf16)f1.z; v[7] = (__bf16)f1.w;
      lb[nf] = v;
    } else lb[nf] = zz;
  }
#pragma unroll
  for (int mf = 0; mf < 8; ++mf)
#pragma unroll
    for (int nf = 0; nf < 2; ++nf)
      accu[mf][nf] = __builtin_amdgcn_mfma_f32_16x16x32_bf16(la[mf], lb[nf], accu[mf][nf], 0, 0, 0);

#pragma unroll
  for (int mf = 0; mf < 8; ++mf)
#pragma unroll
    for (int nf = 0; nf < 2; ++nf)
#pragma unroll
      for (int j2 = 0; j2 < 4; ++j2) {
        int row = m0 + wm * 128 + mf * 16 + kg * 4 + j2;
        int col = n0 + wn * 32 + nf * 16 + lr;
        float g = accg[mf][nf][j2], uu = accu[mf][nf][j2];
        float s = g / (1.f + __expf(-g));
        act[(size_t)row * F + col] = f2b(s * uu);
      }
}

// ====== down GEMM, 256m x 128n, NO K-split, 4-phase/2-K-tile, fp32 out =========
#define STAGE_NA(buf, half, kt) do {                                           \
    const u16* gs_ = Ab + (size_t)(m0 + (half) * 128) * 11008 + (size_t)(kt) * 64; \
    u16* ld_ = sA + (buf) * 16384 + (half) * 8192;                             \
    _Pragma("unroll")                                                          \
    for (int i_ = 0; i_ < 2; ++i_) {                                           \
      int ub_ = (wid << 6) + i_ * 512;                                         \
      int un_ = ub_ + lane;                                                    \
      int ur_ = un_ >> 3, us_ = (un_ & 7) ^ (ur_ & 7);                         \
      GLDS16(gs_ + (size_t)ur_ * 11008 + us_ * 8, ld_ + ub_ * 8);              \
    }                                                                          \
  } while (0)

#define STAGE_NB(buf, kt) do {                                                 \
    const u16* gs_ = Wd + (size_t)n0 * 11008 + (size_t)(kt) * 64;              \
    u16* ld_ = sB + (buf) * 8192;                                              \
    _Pragma("unroll")                                                          \
    for (int i_ = 0; i_ < 2; ++i_) {                                           \
      int ub_ = (wid << 6) + i_ * 512;                                         \
      int un_ = ub_ + lane;                                                    \
      int ur_ = un_ >> 3, us_ = (un_ & 7) ^ (ur_ & 7);                         \
      GLDS16(gs_ + (size_t)ur_ * 11008 + us_ * 8, ld_ + ub_ * 8);              \
    }                                                                          \
  } while (0)

#define KTW(t) ((t) >= 172 ? (t) - 172 : (t))

__global__ __launch_bounds__(512, 2) void gemm_down_ns(
    const u16* __restrict__ Ab, const u16* __restrict__ Wd,
    const u16* __restrict__ td, const float* __restrict__ Bd,
    const int* __restrict__ lidx, const int* __restrict__ layer,
    float* __restrict__ out) {
  constexpr int H = 4096;
  extern __shared__ u16 smem[];
  u16* sA = smem;            // [2][256*64] 64 KB
  u16* sB = smem + 32768;    // [2][128*64] 32 KB
  const int b = blockIdx.x;
  const int xcd = b & 7, j = b >> 3;
  const int ny = xcd + 8 * (j >> 3);   // 32 n-tiles, 8 % == 0 -> bijective
  const int mx = j & 7;
  const int tid = threadIdx.x, lane = tid & 63, wid = tid >> 6;
  const int lr = lane & 15, kg = lane >> 4, rx = lr & 7;
  const int wm = wid >> 2, wn = wid & 3;
  const int m0 = mx * 256;
  const int n0 = ny * 128;

  f32x4 acc[8][2] = {};
  bf16x8 a0[4][2], a1[4][2], bw[2][2];

  STAGE_NA(0, 0, 0); STAGE_NA(0, 1, 0); STAGE_NB(0, 0);
  STAGE_NA(1, 0, 1); STAGE_NB(1, 1);
  WAIT_VM0(); BAR();

#pragma unroll 1
  for (int u = 0; u < 86; ++u) {
    const int ktA = KTW(2 * u + 1);
    const int kt0 = KTW(2 * u + 2);
    const int kt1 = KTW(2 * u + 3);
    // g1: compute buf0-lo; stage buf1.A1 (tile 2u+1)
    RD_A(a0, 0, 0); RD_BW(bw, sB, 0);
    STAGE_NA(1, 1, ktA);
    BAR(); WAIT_LGKM0();
    MMA_F(a0, bw, acc, 0);
    BAR();
    // g2: compute buf0-hi (b reused in regs); stage buf0-next A0+B
    RD_A(a1, 0, 1);
    STAGE_NA(0, 0, kt0); STAGE_NB(0, kt0);
    BAR(); WAIT_LGKM0();
    MMA_F(a1, bw, acc, 4);
    WAIT_VM4();
    BAR();
    // g3: compute buf1-lo; stage buf0-next A1
    RD_A(a0, 1, 0); RD_BW(bw, sB, 1);
    STAGE_NA(0, 1, kt0);
    BAR(); WAIT_LGKM0();
    MMA_F(a0, bw, acc, 0);
    BAR();
    // g4: compute buf1-hi; stage buf1-next A0+B
    RD_A(a1, 1, 1);
    STAGE_NA(1, 0, kt1); STAGE_NB(1, kt1);
    BAR(); WAIT_LGKM0();
    MMA_F(a1, bw, acc, 4);
    WAIT_VM4();
    BAR();
  }

  // ---- down-LoRA via MFMA (K=16 padded to 32), then fp32 store ----
  const int li = lidx[m0 >> 9];
  const size_t bbase = ((size_t)layer[0] * 16 + li) * (size_t)H * 16;
  bf16x8 la[8], lb[2];
  const bf16x8 zz = {};
#pragma unroll
  for (int mf = 0; mf < 8; ++mf) {
    int row = m0 + wm * 128 + mf * 16 + lr;
    la[mf] = (kg < 2) ? *(const bf16x8*)&td[(size_t)row * 16 + kg * 8] : zz;
  }
#pragma unroll
  for (int nf = 0; nf < 2; ++nf) {
    int col = n0 + wn * 32 + nf * 16 + lr;
    if (kg < 2) {
      const float* bp = Bd + bbase + (size_t)col * 16 + kg * 8;
      float4 f0 = *(const float4*)bp;
      float4 f1 = *(const float4*)(bp + 4);
      bf16x8 v;
      v[0] = (__bf16)f0.x; v[1] = (__bf16)f0.y; v[2] = (__bf16)f0.z; v[3] = (__bf16)f0.w;
      v[4] = (__bf16)f1.x; v[5] = (__bf16)f1.y; v[6] = (__bf16)f1.z; v[7] = (__bf16)f1.w;
      lb[nf] = v;
    } else lb[nf] = zz;
  }
#pragma unroll
  for (int mf = 0; mf < 8; ++mf)
#pragma unroll
    for (int nf = 0; nf < 2; ++nf)
      acc[mf][nf] = __builtin_amdgcn_mfma_f32_16x16x32_bf16(la[mf], lb[nf], acc[mf][nf], 0, 0, 0);

#pragma unroll
  for (int mf = 0; mf < 8; ++mf)
#pragma unroll
    for (int nf = 0; nf < 2; ++nf)
#pragma unroll
      for (int j2 = 0; j2 < 4; ++j2) {
        int row = m0 + wm * 128 + mf * 16 + kg * 4 + j2;
        int col = n0 + wn * 32 + nf * 16 + lr;
        out[(size_t)row * H + col] = acc[mf][nf][j2];
      }
}

extern "C" void kernel_launch(void* const* d_in, const int* in_sizes, int n_in,
                              void* d_out, int out_size, void* d_ws, size_t ws_size,
                              hipStream_t stream) {
  const float* x  = (const float*)d_in[0];
  const float* Wg = (const float*)d_in[1];
  const float* Wu = (const float*)d_in[2];
  const float* Wd = (const float*)d_in[3];
  const float* Ag = (const float*)d_in[4];
  const float* Bg = (const float*)d_in[5];
  const float* Au = (const float*)d_in[6];
  const float* Bu = (const float*)d_in[7];
  const float* Ad = (const float*)d_in[8];
  const float* Bd = (const float*)d_in[9];
  const int* lidx = (const int*)d_in[10];
  const int* lay  = (const int*)d_in[11];
  float* out = (float*)d_out;

  char* ws = (char*)d_ws;
  u16*  xb   = (u16*)(ws + 0);            //  16,777,216  x bf16 [2048][4096]
  u16*  wgb  = (u16*)(ws + 16777216);     //  90,177,536  Wg bf16 [11008][4096]
  u16*  wub  = (u16*)(ws + 106954752);    //  90,177,536  Wu bf16
  u16*  gbuf = (u16*)(ws + 197132288);    //  45,088,768  act bf16 [2048][11008]
  u16*  tg   = (u16*)(ws + 287309824);    //  65,536
  u16*  tu   = (u16*)(ws + 287375360);    //  65,536
  u16*  td   = (u16*)(ws + 287440896);    //  65,536
  u16*  wdb3 = (u16*)(ws + 287506432);    //  90,177,536  Wd bf16

  hipFuncSetAttribute(reinterpret_cast<const void*>(gemm_gup_fused),
                      hipFuncAttributeMaxDynamicSharedMemorySize, 131072);
  hipFuncSetAttribute(reinterpret_cast<const void*>(gemm_down_ns),
                      hipFuncAttributeMaxDynamicSharedMemorySize, 98304);

  cvt3_kernel<<<4608, 256, 0, stream>>>((const float4*)x,  (ushort4*)xb,
                                        (const float4*)Wg, (ushort4*)wgb,
                                        (const float4*)Wu, (ushort4*)wub);

  lora_t2<<<128, 256, 0, stream>>>(xb, 4096, Ag, Au, lidx, lay, tg, tu);

  gemm_gup_fused<<<dim3(960), 512, 131072, stream>>>(
      xb, wgb, wub, tg, tu, Bg, Bu, lidx, lay, gbuf,
      (const float4*)Wd, (ushort4*)wdb3);

  lora_t2<<<128, 256, 0, stream>>>(gbuf, 11008, Ad, nullptr, lidx, lay, td, nullptr);

  gemm_down_ns<<<dim3(256), 512, 98304, stream>>>(gbuf, wdb3, td, Bd, lidx, lay, out);
}